// Round 4
// baseline (1165.306 us; speedup 1.0000x reference)
//
#include <hip/hip_runtime.h>
#include <hip/hip_bf16.h>
#include <math.h>

// ---------------------------------------------------------------------------
// WaveNet inference, fp32, right-aligned suffix computation.
// Derivations (verified round 2/3, absmax 2.4e-4):
//  - dilate() batch-folding == time-domain dilated 2-tap conv: out[t] uses
//    taps X[t], X[t+d]; residual adds X[t+d].
//  - x_skip is OVERWRITTEN each layer -> only layer 39's skip matters, and
//    its input is h = tanh*sigmoid (BEFORE the residual conv).
//  - output needs only the trailing 4096+4092=8188 samples of start conv.
// Round 4: fuse 5 layers per launch in LDS. Dilations per 10-layer block are
// 1..16 (halo 31) then 32..512; folding t=32q+r turns the latter into
// q-space dilations 1..16 (halo 31 again). 40 layer launches -> 8.
// ---------------------------------------------------------------------------

#define TS   8192
#define T0   8188
#define NB   8
#define RCH  32
#define CLS  256
#define TOUT 4096

// workspace layout (float offsets)
#define OFF_WBLOB 0                      // 40 * 5120  (wf[ic][k][oc], wg, wr[ic][oc])
#define OFF_ST    204800                 // start_w^T  [ic][oc]
#define OFF_SK    212992                 // skip_w[39]^T [dc][sc]
#define OFF_E1T   221184                 // end1^T [sc][ec]
#define OFF_E2T   286720                 // end2^T [ec][cc]
#define OFF_XA    352256                 // NB*RCH*TS
#define OFF_XB    (OFF_XA + NB*RCH*TS)
#define OFF_H1    (OFF_XB + NB*RCH*TS)   // NB*256*TOUT
#define OFF_E1    (OFF_H1 + NB*256*TOUT)

__device__ __forceinline__ float tanh_fast(float x) {
    float e = __expf(2.0f * x);
    return 1.0f - 2.0f / (e + 1.0f);
}
__device__ __forceinline__ float sigmoid_fast(float x) {
    return 1.0f / (1.0f + __expf(-x));
}

// ---------------------------------------------------------------------------
__global__ void repack_kernel(const float* __restrict__ start_w,
                              const float* __restrict__ filter_w,
                              const float* __restrict__ gate_w,
                              const float* __restrict__ residual_w,
                              const float* __restrict__ skip_w,
                              const float* __restrict__ end1_w,
                              const float* __restrict__ end2_w,
                              float* __restrict__ ws) {
    int id = blockIdx.x * 256 + threadIdx.x;
    if (id < 204800) {
        int l = id / 5120, r = id % 5120;
        float v;
        if (r < 4096) {                      // wf then wg: [ic][k][oc]
            const float* src = (r < 2048) ? filter_w : gate_w;
            int rr = r & 2047;
            int ic = rr >> 6, k = (rr >> 5) & 1, oc = rr & 31;
            v = src[((l * 32 + oc) * 32 + ic) * 2 + k];
        } else {                             // wr: [ic][oc]
            int rr = r - 4096;
            int ic = rr >> 5, oc = rr & 31;
            v = residual_w[(l * 32 + oc) * 32 + ic];
        }
        ws[OFF_WBLOB + id] = v;
    } else if (id < 204800 + 8192) {
        int r = id - 204800;
        int ic = r >> 5, oc = r & 31;
        ws[OFF_ST + r] = start_w[oc * 256 + ic];
    } else if (id < 212992 + 8192) {
        int r = id - 212992;
        int dc = r >> 8, sc = r & 255;
        ws[OFF_SK + r] = skip_w[(39 * 256 + sc) * 32 + dc];
    } else if (id < 221184 + 65536) {
        int r = id - 221184;
        int sc = r >> 8, ec = r & 255;
        ws[OFF_E1T + r] = end1_w[ec * 256 + sc];
    } else if (id < 286720 + 65536) {
        int r = id - 286720;
        int ec = r >> 8, cc = r & 255;
        ws[OFF_E2T + r] = end2_w[cc * 256 + ec];
    }
}

// ---------------------------------------------------------------------------
// start conv, 16 outputs/thread
__global__ __launch_bounds__(256) void start_kernel(const float* __restrict__ xin,
                                                    const float* __restrict__ st,
                                                    float* __restrict__ xout) {
    int t = blockIdx.x * 256 + threadIdx.x;
    int og = blockIdx.y;
    int b = blockIdx.z;
    if (t >= T0) return;
    const float* xi = xin + (size_t)b * 256 * 16384 + (16384 - T0) + t;
    const float* wb = st + og * 16;
    float acc[16];
#pragma unroll
    for (int c = 0; c < 16; c++) acc[c] = 0.f;
#pragma unroll 4
    for (int ic = 0; ic < 256; ic++) {
        float xv = xi[ic * 16384];
        const float* w = wb + ic * 32;
#pragma unroll
        for (int c = 0; c < 16; c++) acc[c] = fmaf(w[c], xv, acc[c]);
    }
    float* xo = xout + ((size_t)(b * RCH) + og * 16) * TS + t;
#pragma unroll
    for (int c = 0; c < 16; c++) xo[c * TS] = acc[c];
}

// ---------------------------------------------------------------------------
// 5-layer fused core on LDS tiles. Bin/Bout ping-pong, H for gated acts.
// Layer j: dilation d=1<<j. Phase1: conv reads Bin -> H. Phase2: residual
// reads H + Bin[p+d] -> Bout. 2 syncs/layer; no intra-phase races.
// lastGrp: layer j==4 is global layer 39 -> Bout = h (residual path dead).
__device__ __forceinline__ void run5(float (*B0)[160], float (*B1)[160],
                                     float (*Hb)[160], const float* wl,
                                     int E0, int tx, int cg, bool lastGrp) {
    int E = E0;
#pragma unroll 1
    for (int j = 0; j < 5; j++) {
        int d = 1 << j;
        int L = E - d;
        float (*Bin)[160]  = (j & 1) ? B1 : B0;
        float (*Bout)[160] = (j & 1) ? B0 : B1;
        const float* wf = wl +        cg * 8;     // wf[ic*64 + k*32 + oc8]
        const float* wg = wl + 2048 + cg * 8;
        const float* wr = wl + 4096 + cg * 8;     // wr[ic*32 + oc8]

        for (int p = tx; p < L; p += 64) {
            float accf[8], accg[8];
#pragma unroll
            for (int o = 0; o < 8; o++) { accf[o] = 0.f; accg[o] = 0.f; }
#pragma unroll 8
            for (int ic = 0; ic < 32; ic++) {
                float a = Bin[ic][p];
                float c = Bin[ic][p + d];
                const float* w0 = wf + ic * 64;
                const float* w1 = wg + ic * 64;
#pragma unroll
                for (int o = 0; o < 8; o++) accf[o] = fmaf(w0[o],      a, accf[o]);
#pragma unroll
                for (int o = 0; o < 8; o++) accf[o] = fmaf(w0[32 + o], c, accf[o]);
#pragma unroll
                for (int o = 0; o < 8; o++) accg[o] = fmaf(w1[o],      a, accg[o]);
#pragma unroll
                for (int o = 0; o < 8; o++) accg[o] = fmaf(w1[32 + o], c, accg[o]);
            }
#pragma unroll
            for (int o = 0; o < 8; o++)
                Hb[cg * 8 + o][p] = tanh_fast(accf[o]) * sigmoid_fast(accg[o]);
        }
        __syncthreads();

        if (lastGrp && j == 4) {
            for (int p = tx; p < L; p += 64)
#pragma unroll
                for (int o = 0; o < 8; o++) Bout[cg * 8 + o][p] = Hb[cg * 8 + o][p];
        } else {
            for (int p = tx; p < L; p += 64) {
                float acc[8];
#pragma unroll
                for (int o = 0; o < 8; o++) acc[o] = Bin[cg * 8 + o][p + d];  // residual X[t+d]
#pragma unroll 8
                for (int ic = 0; ic < 32; ic++) {
                    float hv = Hb[ic][p];
#pragma unroll
                    for (int o = 0; o < 8; o++) acc[o] = fmaf(wr[ic * 32 + o], hv, acc[o]);
                }
#pragma unroll
                for (int o = 0; o < 8; o++) Bout[cg * 8 + o][p] = acc[o];
            }
        }
        __syncthreads();
        E = L;
        wl += 5120;
    }
    // result of 5 layers is in B1 (j=4 even -> Bout == B1)
}

// ---------------------------------------------------------------------------
// fused small-dilation group (d=1..16), t-contiguous tiles of 128 (+31 halo)
__global__ __launch_bounds__(256) void fuse5_t(const float* __restrict__ xin,
                                               float* __restrict__ xout,
                                               const float* __restrict__ wl0,
                                               int T_in, int T_a) {
    __shared__ float B0[32][160], B1[32][160], Hb[32][160];
    int tx = threadIdx.x;
    int cg = __builtin_amdgcn_readfirstlane(threadIdx.y);
    int tid = threadIdx.y * 64 + tx;
    int t0 = blockIdx.x * 128;
    int b  = blockIdx.y;
    int E0 = min(159, T_in - t0);
    const float* xr = xin + (size_t)(b * 32) * TS + t0;
#pragma unroll 4
    for (int ch = 0; ch < 32; ch++)
        if (tid < E0) B0[ch][tid] = xr[(size_t)ch * TS + tid];
    __syncthreads();

    run5(B0, B1, Hb, wl0, E0, tx, cg, false);

    int valid = min(128, T_a - t0);
    float* xo = xout + (size_t)(b * 32) * TS + t0;
#pragma unroll 4
    for (int ch = 0; ch < 32; ch++)
        if (tid < valid) xo[(size_t)ch * TS + tid] = B1[ch][tid];
}

// ---------------------------------------------------------------------------
// fused large-dilation group (d=32..512) folded by 32: t = 32q + r.
// Per (b, r, q-chunk): q-space dilations 1..16, halo 31.
__global__ __launch_bounds__(256) void fuse5_q(const float* __restrict__ yin,
                                               float* __restrict__ zout,
                                               const float* __restrict__ wl0,
                                               int T_b, int T_z, int lastGrp) {
    __shared__ float B0[32][160], B1[32][160], Hb[32][160];
    int tx = threadIdx.x;
    int cg = __builtin_amdgcn_readfirstlane(threadIdx.y);
    int tid = threadIdx.y * 64 + tx;
    int q0 = blockIdx.x * 128;
    int r  = blockIdx.y;
    int b  = blockIdx.z;
    int Qr = (T_b - r + 31) >> 5;            // #valid q for this residue
    int E0 = min(159, Qr - q0);
    const float* yb = yin + (size_t)(b * 32) * TS + r;
#pragma unroll 4
    for (int ch = 0; ch < 32; ch++)
        if (tid < E0) B0[ch][tid] = yb[(size_t)ch * TS + ((q0 + tid) << 5)];
    __syncthreads();

    run5(B0, B1, Hb, wl0, E0, tx, cg, lastGrp != 0);

    int Qz = (T_z - r + 31) >> 5;
    int valid = min(128, Qz - q0);
    float* zb = zout + (size_t)(b * 32) * TS + r;
#pragma unroll 4
    for (int ch = 0; ch < 32; ch++)
        if (tid < valid) zb[(size_t)ch * TS + ((q0 + tid) << 5)] = B1[ch][tid];
}

// ---------------------------------------------------------------------------
// skip conv + relu, 32 outputs/thread
__global__ __launch_bounds__(256) void skip_kernel(const float* __restrict__ xin,
                                                   const float* __restrict__ sk,
                                                   float* __restrict__ h1) {
    int t = blockIdx.x * 256 + threadIdx.x;
    int sg = blockIdx.y;
    int b = blockIdx.z;
    const float* xi = xin + (size_t)(b * RCH) * TS + t;
    const float* wb = sk + sg * 32;
    float acc[32];
#pragma unroll
    for (int j = 0; j < 32; j++) acc[j] = 0.f;
#pragma unroll 4
    for (int dc = 0; dc < 32; dc++) {
        float xv = xi[dc * TS];
        const float* w = wb + dc * 256;
#pragma unroll
        for (int j = 0; j < 32; j++) acc[j] = fmaf(w[j], xv, acc[j]);
    }
    float* ho = h1 + ((size_t)(b * 256) + sg * 32) * TOUT + t;
#pragma unroll
    for (int j = 0; j < 32; j++) ho[j * TOUT] = fmaxf(acc[j], 0.f);
}

// end1 + bias + relu, 32 outputs/thread
__global__ __launch_bounds__(256) void end1_kernel(const float* __restrict__ h1,
                                                   const float* __restrict__ e1t,
                                                   const float* __restrict__ b1,
                                                   float* __restrict__ e1) {
    int t = blockIdx.x * 256 + threadIdx.x;
    int eg = blockIdx.y;
    int b = blockIdx.z;
    const float* hp = h1 + (size_t)(b * 256) * TOUT + t;
    const float* wb = e1t + eg * 32;
    float acc[32];
#pragma unroll
    for (int j = 0; j < 32; j++) acc[j] = b1[eg * 32 + j];
#pragma unroll 4
    for (int sc = 0; sc < 256; sc++) {
        float xv = hp[sc * TOUT];
        const float* w = wb + sc * 256;
#pragma unroll
        for (int j = 0; j < 32; j++) acc[j] = fmaf(w[j], xv, acc[j]);
    }
    float* ep = e1 + ((size_t)(b * 256) + eg * 32) * TOUT + t;
#pragma unroll
    for (int j = 0; j < 32; j++) ep[j * TOUT] = fmaxf(acc[j], 0.f);
}

// end2 + bias, transposed store, 32 outputs/thread
__global__ __launch_bounds__(256) void end2_kernel(const float* __restrict__ e1,
                                                   const float* __restrict__ e2t,
                                                   const float* __restrict__ b2,
                                                   float* __restrict__ out) {
    int t = blockIdx.x * 256 + threadIdx.x;
    int cg = blockIdx.y;
    int b = blockIdx.z;
    const float* ep = e1 + (size_t)(b * 256) * TOUT + t;
    const float* wb = e2t + cg * 32;
    float acc[32];
#pragma unroll
    for (int j = 0; j < 32; j++) acc[j] = b2[cg * 32 + j];
#pragma unroll 4
    for (int ec = 0; ec < 256; ec++) {
        float xv = ep[ec * TOUT];
        const float* w = wb + ec * 256;
#pragma unroll
        for (int j = 0; j < 32; j++) acc[j] = fmaf(w[j], xv, acc[j]);
    }
    float* op = out + ((size_t)(b * TOUT + t)) * CLS + cg * 32;
#pragma unroll
    for (int j = 0; j < 8; j++)
        ((float4*)op)[j] = make_float4(acc[4*j], acc[4*j+1], acc[4*j+2], acc[4*j+3]);
}

// ---------------------------------------------------------------------------
extern "C" void kernel_launch(void* const* d_in, const int* in_sizes, int n_in,
                              void* d_out, int out_size, void* d_ws, size_t ws_size,
                              hipStream_t stream) {
    const float* x_input    = (const float*)d_in[0];
    const float* start_w    = (const float*)d_in[1];
    const float* filter_w   = (const float*)d_in[2];
    const float* gate_w     = (const float*)d_in[3];
    const float* residual_w = (const float*)d_in[4];
    const float* skip_w     = (const float*)d_in[5];
    const float* end1_w     = (const float*)d_in[6];
    const float* end1_b     = (const float*)d_in[7];
    const float* end2_w     = (const float*)d_in[8];
    const float* end2_b     = (const float*)d_in[9];
    float* ws  = (float*)d_ws;
    float* out = (float*)d_out;

    repack_kernel<<<dim3((352256 + 255) / 256), 256, 0, stream>>>(
        start_w, filter_w, gate_w, residual_w, skip_w, end1_w, end2_w, ws);

    start_kernel<<<dim3(32, 2, NB), 256, 0, stream>>>(
        x_input, ws + OFF_ST, ws + OFF_XA);

    // per 10-layer block: T_in -> (small d=1..16) T_a -> (big d=32..512) T_z
    const int Tin_g[4] = { 8188, 7165, 6142, 5119 };
    const int Ta_g[4]  = { 8157, 7134, 6111, 5088 };
    const int Tz_g[4]  = { 7165, 6142, 5119, 4096 };

    float* bufs[2] = { ws + OFF_XA, ws + OFF_XB };
    int cur = 0;
    for (int g = 0; g < 4; g++) {
        int gxA = (Ta_g[g] + 127) / 128;
        fuse5_t<<<dim3(gxA, NB), dim3(64, 4), 0, stream>>>(
            bufs[cur], bufs[cur ^ 1], ws + OFF_WBLOB + (size_t)(g * 10) * 5120,
            Tin_g[g], Ta_g[g]);
        cur ^= 1;
        int Qz = (Tz_g[g] + 31) / 32;
        int gxB = (Qz + 127) / 128;
        fuse5_q<<<dim3(gxB, 32, NB), dim3(64, 4), 0, stream>>>(
            bufs[cur], bufs[cur ^ 1], ws + OFF_WBLOB + (size_t)(g * 10 + 5) * 5120,
            Ta_g[g], Tz_g[g], g == 3);
        cur ^= 1;
    }
    // h of layer 39 in bufs[cur], T = 4096

    skip_kernel<<<dim3(16, 8, NB), 256, 0, stream>>>(bufs[cur], ws + OFF_SK, ws + OFF_H1);
    end1_kernel<<<dim3(16, 8, NB), 256, 0, stream>>>(ws + OFF_H1, ws + OFF_E1T, end1_b, ws + OFF_E1);
    end2_kernel<<<dim3(16, 8, NB), 256, 0, stream>>>(ws + OFF_E1, ws + OFF_E2T, end2_b, out);
}

// Round 5
// 953.876 us; speedup vs baseline: 1.2217x; 1.2217x over previous
//
#include <hip/hip_runtime.h>
#include <hip/hip_bf16.h>
#include <math.h>

// ---------------------------------------------------------------------------
// WaveNet inference, fp32, right-aligned suffix computation.
// Derivations (verified rounds 2-4, absmax 2.4e-4):
//  - dilate() batch-folding == time-domain dilated 2-tap conv: out[t] uses
//    taps X[t], X[t+d]; residual adds X[t+d].
//  - x_skip is OVERWRITTEN each layer -> only layer 39's skip matters, and
//    its input is h = tanh*sigmoid (BEFORE the residual conv).
//  - output needs only the trailing 4096+4092=8188 samples of start conv.
// Round 5: r4's 5-layer LDS fusion REGRESSED (118us/launch, 2 waves/SIMD,
// barrier-serialized). Revert to per-layer kernels; fix r3's latency bound
// instead: block (64,8), grid ~1024 -> 32 waves/CU, stage tap windows in
// small LDS (24KB) once per block, compute VALU-bound from LDS.
// ---------------------------------------------------------------------------

#define TS   8192
#define T0   8188
#define NB   8
#define RCH  32
#define CLS  256
#define TOUT 4096

// workspace layout (float offsets)
#define OFF_WBLOB 0                      // 40 * 5120  (wf[ic][k][oc], wg, wr[ic][oc])
#define OFF_ST    204800                 // start_w^T  [ic][oc]
#define OFF_SK    212992                 // skip_w[39]^T [dc][sc]
#define OFF_E1T   221184                 // end1^T [sc][ec]
#define OFF_E2T   286720                 // end2^T [ec][cc]
#define OFF_XA    352256                 // NB*RCH*TS
#define OFF_XB    (OFF_XA + NB*RCH*TS)
#define OFF_H1    (OFF_XB + NB*RCH*TS)   // NB*256*TOUT
#define OFF_E1    (OFF_H1 + NB*256*TOUT)

__device__ __forceinline__ float tanh_fast(float x) {
    float e = __expf(2.0f * x);
    return 1.0f - 2.0f / (e + 1.0f);
}
__device__ __forceinline__ float sigmoid_fast(float x) {
    return 1.0f / (1.0f + __expf(-x));
}

// ---------------------------------------------------------------------------
__global__ void repack_kernel(const float* __restrict__ start_w,
                              const float* __restrict__ filter_w,
                              const float* __restrict__ gate_w,
                              const float* __restrict__ residual_w,
                              const float* __restrict__ skip_w,
                              const float* __restrict__ end1_w,
                              const float* __restrict__ end2_w,
                              float* __restrict__ ws) {
    int id = blockIdx.x * 256 + threadIdx.x;
    if (id < 204800) {
        int l = id / 5120, r = id % 5120;
        float v;
        if (r < 4096) {                      // wf then wg: [ic][k][oc]
            const float* src = (r < 2048) ? filter_w : gate_w;
            int rr = r & 2047;
            int ic = rr >> 6, k = (rr >> 5) & 1, oc = rr & 31;
            v = src[((l * 32 + oc) * 32 + ic) * 2 + k];
        } else {                             // wr: [ic][oc]
            int rr = r - 4096;
            int ic = rr >> 5, oc = rr & 31;
            v = residual_w[(l * 32 + oc) * 32 + ic];
        }
        ws[OFF_WBLOB + id] = v;
    } else if (id < 204800 + 8192) {
        int r = id - 204800;
        int ic = r >> 5, oc = r & 31;
        ws[OFF_ST + r] = start_w[oc * 256 + ic];
    } else if (id < 212992 + 8192) {
        int r = id - 212992;
        int dc = r >> 8, sc = r & 255;
        ws[OFF_SK + r] = skip_w[(39 * 256 + sc) * 32 + dc];
    } else if (id < 221184 + 65536) {
        int r = id - 221184;
        int sc = r >> 8, ec = r & 255;
        ws[OFF_E1T + r] = end1_w[ec * 256 + sc];
    } else if (id < 286720 + 65536) {
        int r = id - 286720;
        int ec = r >> 8, cc = r & 255;
        ws[OFF_E2T + r] = end2_w[cc * 256 + ec];
    }
}

// ---------------------------------------------------------------------------
// start conv, LDS-staged in K-chunks of 32; block (64,8), 4 oc/thread
__global__ __launch_bounds__(512) void start_kernel(const float* __restrict__ xin,
                                                    const float* __restrict__ st,
                                                    float* __restrict__ xout) {
    __shared__ float S[32][64];
    int tx = threadIdx.x, ty = threadIdx.y;
    int cg = __builtin_amdgcn_readfirstlane(ty);
    int tid = ty * 64 + tx;
    int t0 = blockIdx.x * 64;
    int b  = blockIdx.y;
    int t  = t0 + tx;
    const float* xb = xin + (size_t)b * 256 * 16384 + (16384 - T0);
    float acc[4] = {0.f, 0.f, 0.f, 0.f};
    for (int k0 = 0; k0 < 256; k0 += 32) {
        if (k0) __syncthreads();
        for (int i = tid; i < 2048; i += 512) {
            int ic = i >> 6, tt = i & 63;
            int tg = t0 + tt;
            S[ic][tt] = (tg < T0) ? xb[(size_t)(k0 + ic) * 16384 + tg] : 0.f;
        }
        __syncthreads();
        const float* wbase = st + (size_t)k0 * 32 + cg * 4;
#pragma unroll 8
        for (int i = 0; i < 32; i++) {
            float xv = S[i][tx];
            const float* w = wbase + i * 32;
#pragma unroll
            for (int o = 0; o < 4; o++) acc[o] = fmaf(w[o], xv, acc[o]);
        }
    }
    if (t < T0) {
        float* xo = xout + ((size_t)(b * RCH) + cg * 4) * TS + t;
#pragma unroll
        for (int o = 0; o < 4; o++) xo[o * TS] = acc[o];
    }
}

// ---------------------------------------------------------------------------
// one WaveNet layer. Block (64,8): 64 timesteps, 8 oc-groups of 4.
// Stage tap windows A=x[t0..t0+64), C=x[t0+d..t0+d+64) in LDS once per
// block (coalesced), then conv/gate/residual fully from LDS (2-way lane
// aliasing on 32 banks = free). last!=0 (layer 39): store h, skip residual.
__global__ __launch_bounds__(512) void layer_kernel(const float* __restrict__ xin,
                                                    float* __restrict__ xout,
                                                    const float* __restrict__ wl,
                                                    int d, int Tout, int last) {
    __shared__ float A[32][64], C[32][64], Hs[32][64];
    int tx = threadIdx.x, ty = threadIdx.y;
    int cg = __builtin_amdgcn_readfirstlane(ty);
    int tid = ty * 64 + tx;
    int t0 = blockIdx.x * 64;
    int b  = blockIdx.y;
    int t  = t0 + tx;
    const float* xb = xin + (size_t)(b * RCH) * TS;
    for (int i = tid; i < 2048; i += 512) {
        int ch = i >> 6, tt = i & 63;
        A[ch][tt] = xb[(size_t)ch * TS + t0 + tt];
        C[ch][tt] = xb[(size_t)ch * TS + t0 + d + tt];   // overreads stay in d_ws
    }
    __syncthreads();

    const float* wf = wl +        cg * 4;    // wf[ic*64 + k*32 + oc]
    const float* wg = wl + 2048 + cg * 4;
    const float* wr = wl + 4096 + cg * 4;    // wr[ic*32 + oc]

    float accf[4] = {0.f, 0.f, 0.f, 0.f}, accg[4] = {0.f, 0.f, 0.f, 0.f};
#pragma unroll 8
    for (int ic = 0; ic < 32; ic++) {
        float a = A[ic][tx];
        float c = C[ic][tx];
        const float* w0 = wf + ic * 64;
        const float* w1 = wg + ic * 64;
#pragma unroll
        for (int o = 0; o < 4; o++) accf[o] = fmaf(w0[o],      a, accf[o]);
#pragma unroll
        for (int o = 0; o < 4; o++) accf[o] = fmaf(w0[32 + o], c, accf[o]);
#pragma unroll
        for (int o = 0; o < 4; o++) accg[o] = fmaf(w1[o],      a, accg[o]);
#pragma unroll
        for (int o = 0; o < 4; o++) accg[o] = fmaf(w1[32 + o], c, accg[o]);
    }

    float h[4];
#pragma unroll
    for (int o = 0; o < 4; o++) h[o] = tanh_fast(accf[o]) * sigmoid_fast(accg[o]);

    if (last) {                              // layer 39: only h is consumed
        if (t < Tout) {
            float* xo = xout + ((size_t)(b * RCH) + cg * 4) * TS + t;
#pragma unroll
            for (int o = 0; o < 4; o++) xo[o * TS] = h[o];
        }
        return;
    }

#pragma unroll
    for (int o = 0; o < 4; o++) Hs[cg * 4 + o][tx] = h[o];
    __syncthreads();

    float acc[4];
#pragma unroll
    for (int o = 0; o < 4; o++) acc[o] = C[cg * 4 + o][tx];   // residual X[t+d]
#pragma unroll 8
    for (int ic = 0; ic < 32; ic++) {
        float hv = Hs[ic][tx];
#pragma unroll
        for (int o = 0; o < 4; o++) acc[o] = fmaf(wr[ic * 32 + o], hv, acc[o]);
    }
    if (t < Tout) {
        float* xo = xout + ((size_t)(b * RCH) + cg * 4) * TS + t;
#pragma unroll
        for (int o = 0; o < 4; o++) xo[o * TS] = acc[o];
    }
}

// ---------------------------------------------------------------------------
// skip conv + relu; block (64,8), 32 sc/thread, K=32 staged once
__global__ __launch_bounds__(512) void skip_kernel(const float* __restrict__ xin,
                                                   const float* __restrict__ sk,
                                                   float* __restrict__ h1) {
    __shared__ float S[32][64];
    int tx = threadIdx.x, ty = threadIdx.y;
    int cg = __builtin_amdgcn_readfirstlane(ty);
    int tid = ty * 64 + tx;
    int t0 = blockIdx.x * 64;
    int b  = blockIdx.y;
    int t  = t0 + tx;
    const float* xb = xin + (size_t)(b * RCH) * TS;
    for (int i = tid; i < 2048; i += 512) {
        int ch = i >> 6, tt = i & 63;
        S[ch][tt] = xb[(size_t)ch * TS + t0 + tt];
    }
    __syncthreads();
    const float* wb = sk + cg * 32;
    float acc[32];
#pragma unroll
    for (int j = 0; j < 32; j++) acc[j] = 0.f;
#pragma unroll 4
    for (int dc = 0; dc < 32; dc++) {
        float xv = S[dc][tx];
        const float* w = wb + dc * 256;
#pragma unroll
        for (int j = 0; j < 32; j++) acc[j] = fmaf(w[j], xv, acc[j]);
    }
    float* ho = h1 + ((size_t)(b * 256) + cg * 32) * TOUT + t;
#pragma unroll
    for (int j = 0; j < 32; j++) ho[j * TOUT] = fmaxf(acc[j], 0.f);
}

// end1 + bias + relu; K=256 staged in chunks of 32
__global__ __launch_bounds__(512) void end1_kernel(const float* __restrict__ h1,
                                                   const float* __restrict__ e1t,
                                                   const float* __restrict__ b1,
                                                   float* __restrict__ e1) {
    __shared__ float S[32][64];
    int tx = threadIdx.x, ty = threadIdx.y;
    int cg = __builtin_amdgcn_readfirstlane(ty);
    int tid = ty * 64 + tx;
    int t0 = blockIdx.x * 64;
    int b  = blockIdx.y;
    int t  = t0 + tx;
    const float* hp = h1 + (size_t)(b * 256) * TOUT;
    const float* wb = e1t + cg * 32;
    float acc[32];
#pragma unroll
    for (int j = 0; j < 32; j++) acc[j] = b1[cg * 32 + j];
    for (int k0 = 0; k0 < 256; k0 += 32) {
        if (k0) __syncthreads();
        for (int i = tid; i < 2048; i += 512) {
            int sc = i >> 6, tt = i & 63;
            S[sc][tt] = hp[(size_t)(k0 + sc) * TOUT + t0 + tt];
        }
        __syncthreads();
#pragma unroll 4
        for (int sc = 0; sc < 32; sc++) {
            float xv = S[sc][tx];
            const float* w = wb + (size_t)(k0 + sc) * 256;
#pragma unroll
            for (int j = 0; j < 32; j++) acc[j] = fmaf(w[j], xv, acc[j]);
        }
    }
    float* ep = e1 + ((size_t)(b * 256) + cg * 32) * TOUT + t;
#pragma unroll
    for (int j = 0; j < 32; j++) ep[j * TOUT] = fmaxf(acc[j], 0.f);
}

// end2 + bias, transposed store; K=256 staged in chunks of 32
__global__ __launch_bounds__(512) void end2_kernel(const float* __restrict__ e1,
                                                   const float* __restrict__ e2t,
                                                   const float* __restrict__ b2,
                                                   float* __restrict__ out) {
    __shared__ float S[32][64];
    int tx = threadIdx.x, ty = threadIdx.y;
    int cg = __builtin_amdgcn_readfirstlane(ty);
    int tid = ty * 64 + tx;
    int t0 = blockIdx.x * 64;
    int b  = blockIdx.y;
    int t  = t0 + tx;
    const float* ep = e1 + (size_t)(b * 256) * TOUT;
    const float* wb = e2t + cg * 32;
    float acc[32];
#pragma unroll
    for (int j = 0; j < 32; j++) acc[j] = b2[cg * 32 + j];
    for (int k0 = 0; k0 < 256; k0 += 32) {
        if (k0) __syncthreads();
        for (int i = tid; i < 2048; i += 512) {
            int ec = i >> 6, tt = i & 63;
            S[ec][tt] = ep[(size_t)(k0 + ec) * TOUT + t0 + tt];
        }
        __syncthreads();
#pragma unroll 4
        for (int ec = 0; ec < 32; ec++) {
            float xv = S[ec][tx];
            const float* w = wb + (size_t)(k0 + ec) * 256;
#pragma unroll
            for (int j = 0; j < 32; j++) acc[j] = fmaf(w[j], xv, acc[j]);
        }
    }
    float* op = out + ((size_t)(b * TOUT + t)) * CLS + cg * 32;
#pragma unroll
    for (int j = 0; j < 8; j++)
        ((float4*)op)[j] = make_float4(acc[4*j], acc[4*j+1], acc[4*j+2], acc[4*j+3]);
}

// ---------------------------------------------------------------------------
extern "C" void kernel_launch(void* const* d_in, const int* in_sizes, int n_in,
                              void* d_out, int out_size, void* d_ws, size_t ws_size,
                              hipStream_t stream) {
    const float* x_input    = (const float*)d_in[0];
    const float* start_w    = (const float*)d_in[1];
    const float* filter_w   = (const float*)d_in[2];
    const float* gate_w     = (const float*)d_in[3];
    const float* residual_w = (const float*)d_in[4];
    const float* skip_w     = (const float*)d_in[5];
    const float* end1_w     = (const float*)d_in[6];
    const float* end1_b     = (const float*)d_in[7];
    const float* end2_w     = (const float*)d_in[8];
    const float* end2_b     = (const float*)d_in[9];
    float* ws  = (float*)d_ws;
    float* out = (float*)d_out;

    repack_kernel<<<dim3((352256 + 255) / 256), 256, 0, stream>>>(
        start_w, filter_w, gate_w, residual_w, skip_w, end1_w, end2_w, ws);

    start_kernel<<<dim3(128, NB), dim3(64, 8), 0, stream>>>(
        x_input, ws + OFF_ST, ws + OFF_XA);

    float* bufs[2] = { ws + OFF_XA, ws + OFF_XB };
    int cur = 0;
    int Tin = T0;
    int cnt = 0;
    for (int bl = 0; bl < 4; bl++) {
        int dd = 1;
        for (int i = 0; i < 10; i++) {
            int Tout_l = Tin - dd;
            layer_kernel<<<dim3((Tout_l + 63) / 64, NB), dim3(64, 8), 0, stream>>>(
                bufs[cur], bufs[cur ^ 1], ws + OFF_WBLOB + (size_t)cnt * 5120,
                dd, Tout_l, cnt == 39);
            cur ^= 1;
            Tin = Tout_l;
            dd *= 2;
            cnt++;
        }
    }
    // Tin == 4096; h of layer 39 in bufs[cur]

    skip_kernel<<<dim3(64, NB), dim3(64, 8), 0, stream>>>(bufs[cur], ws + OFF_SK, ws + OFF_H1);
    end1_kernel<<<dim3(64, NB), dim3(64, 8), 0, stream>>>(ws + OFF_H1, ws + OFF_E1T, end1_b, ws + OFF_E1);
    end2_kernel<<<dim3(64, NB), dim3(64, 8), 0, stream>>>(ws + OFF_E1, ws + OFF_E2T, end2_b, out);
}